// Round 13
// baseline (162.477 us; speedup 1.0000x reference)
//
#include <hip/hip_runtime.h>
#include <cstdint>
#include <cstddef>

#define MAXDET 300
#define IOU_THR 0.6f
#define SCORE_THR 0.05f
#define T0 0.9f          // combined-score compaction threshold (fallback-guarded)
#define CAP 2048         // per-class candidate capacity (expected ~1075)
#define SCAN 512         // NMS scan window over sorted candidates (examined ~345)
#define LCAP 64          // per-block per-class LDS list capacity in score pass
#define SPLIT 128        // blocks per image in score pass
#define BS 1024          // slow-path block size
#define NBUCK 1024       // bucket-sort bins
#define KEYS_MAX 576     // SCAN + slack for the straddling bucket
#define BITS_BASE 0x3F666666u   // float bits of 0.9f (fast-path scores >= 0.9)

typedef unsigned int u32;
typedef unsigned long long u64;

__device__ __forceinline__ float rdlane(float v, int lane) {
    return __uint_as_float(__builtin_amdgcn_readlane(__float_as_uint(v), lane));
}

// ============================ fast path ============================

// Pass 1: coalesced score compute + LDS-aggregated per-class compaction.
__global__ __launch_bounds__(256) void score_compact_kernel(
    const float* __restrict__ cls, const float* __restrict__ cent,
    int N, int C,
    u64* __restrict__ candPacked, int* __restrict__ cntRaw, int* __restrict__ totalCand)
{
    const int b = blockIdx.x / SPLIT;
    const int s = blockIdx.x % SPLIT;
    const int chunk = (N + SPLIT - 1) / SPLIT;
    const int n0 = s * chunk;
    const int n1 = min(n0 + chunk, N);
    const int tid = threadIdx.x;
    const int q  = tid & 3;        // quarter-row: classes 4q..4q+3
    const int ar = tid >> 2;       // anchor offset within 64-anchor tile

    __shared__ int lcnt[16];
    __shared__ int ltot[16];
    __shared__ int lbase[16];
    __shared__ u64 lbuf[16][LCAP];

    if (tid < 16) { lcnt[tid] = 0; ltot[tid] = 0; }
    __syncthreads();

    int myTot[4] = {0, 0, 0, 0};
    for (int n = n0 + ar; n < n1; n += 64) {
        const float4 r = *reinterpret_cast<const float4*>(
            cls + ((size_t)b * N + n) * 16 + q * 4);
        const float ce = cent[(size_t)b * N + n];
        const float cv[4] = {r.x, r.y, r.z, r.w};
#pragma unroll
        for (int u = 0; u < 4; ++u) {
            const float v = cv[u];
            if (v > SCORE_THR) {
                myTot[u]++;
                const float prod = v * ce;
                if (prod >= 0.80f) {                       // conservative pre-filter
                    const float comb = sqrtf(prod);        // exact ref expression
                    if (comb >= T0) {
                        const int c = 4 * q + u;
                        const u64 key = ((u64)__float_as_uint(comb) << 32)
                                      | (u32)(0xFFFFFFFFu - (u32)n);  // score desc, n asc
                        const int lp = atomicAdd(&lcnt[c], 1);
                        if (lp < LCAP) {
                            lbuf[c][lp] = key;
                        } else {  // overflow (astronomically rare): direct append
                            const int pos = atomicAdd(&cntRaw[b * 16 + c], 1);
                            if (pos < CAP)
                                candPacked[((size_t)(b * 16 + c) << 11) + pos] = key;
                        }
                    }
                }
            }
        }
    }
#pragma unroll
    for (int u = 0; u < 4; ++u) atomicAdd(&ltot[4 * q + u], myTot[u]);
    __syncthreads();

    if (tid < 16) {
        const int m = min(lcnt[tid], LCAP);
        lbase[tid] = atomicAdd(&cntRaw[b * 16 + tid], m);   // reserve range
        atomicAdd(&totalCand[b * 16 + tid], ltot[tid]);
    }
    __syncthreads();

    for (int idx = tid; idx < 16 * LCAP; idx += 256) {      // coalesced flush
        const int c = idx >> 6;            // LCAP == 64
        const int k = idx & 63;
        if (k < min(lcnt[c], LCAP)) {
            const int pos = lbase[c] + k;
            if (pos < CAP)
                candPacked[((size_t)(b * 16 + c) << 11) + pos] = lbuf[c][k];
        }
    }
}

// Pass 2 (fused bucket-sort + mask + chunked NMS), one 1024-thread block per (b,c).
// ROUND-13 (phase 7 only; rest byte-identical to round-12 verified):
//  (a) asm-pin the 40-float j-cache -> compiler cannot rematerialize from LDS
//  (b) batch row broadcasts: 2 LDS wave-ops per 8 rows + readlane (scalar pipe)
//  (c) bal[8] register row accumulation + ONE mask[i][ln] write per row
//      (safe now: VGPR cap 128 via waves_per_eu(4,4); round-10 spill was the
//      32-VGPR cap. Guard: WRITE_SIZE must stay ~312KB.)
__global__ __launch_bounds__(1024)
__attribute__((amdgpu_waves_per_eu(4, 4)))
void sort_nms_kernel(
    const float* __restrict__ boxes, const u64* __restrict__ candPacked,
    const int* __restrict__ cntRaw, const int* __restrict__ totalCand,
    int N, int C,
    int* __restrict__ keptIdx, float* __restrict__ keptScore,
    int* __restrict__ keptCnt, int* __restrict__ flagInc)
{
    const int bc  = blockIdx.x;
    const int b   = bc / C;
    const int tid = threadIdx.x;
    const int wv  = tid >> 6;
    const int ln  = tid & 63;
    const int raw = cntRaw[bc];
    const int use = min(raw, CAP);
    const int scanN = min(use, SCAN);
    const float* __restrict__ boxb = boxes + (size_t)b * N * 4;
    const u64* __restrict__ gbase = candPacked + ((size_t)bc << 11);

    __shared__ u64    keyS[KEYS_MAX];      // 4.5 KB sorted keys
    __shared__ float4 sbox4[SCAN];         // 8 KB packed boxes
    __shared__ float  sar[SCAN];           // 2 KB areas
    __shared__ int    scA[NBUCK];          // 4 KB bucket counts
    __shared__ int    scB[NBUCK];          // 4 KB exclusive bases
    __shared__ int    wsum[16];
    __shared__ u64    mask[SCAN][9];       // 36 KB (pad 9 vs 8)
    __shared__ float  ksc[MAXDET];
    __shared__ int    kix[MAXDET];
    __shared__ int    cntSh, flagSh;

    // --- phase 1: zero ---
    scA[tid] = 0;
    if (tid == 0) flagSh = 0;
    __syncthreads();

    // --- phase 2: load + bucket count (2 items/thread, coalesced) ---
    u64 k0 = 0, k1 = 0; int bk0 = -1, bk1 = -1, r0 = 0, r1 = 0;
    if (tid < use) {
        k0 = gbase[tid];
        const u32 bits = (u32)(k0 >> 32);
        const u32 d = bits > BITS_BASE ? bits - BITS_BASE : 0u;
        bk0 = (NBUCK - 1) - (int)min(d >> 11, (u32)(NBUCK - 1));   // high score -> low bucket
        r0 = atomicAdd(&scA[bk0], 1);
    }
    if (tid + 1024 < use) {
        k1 = gbase[tid + 1024];
        const u32 bits = (u32)(k1 >> 32);
        const u32 d = bits > BITS_BASE ? bits - BITS_BASE : 0u;
        bk1 = (NBUCK - 1) - (int)min(d >> 11, (u32)(NBUCK - 1));
        r1 = atomicAdd(&scA[bk1], 1);
    }
    __syncthreads();

    // --- phase 3: exclusive prefix over buckets (wave shfl-scan, 3 barriers) ---
    const int own = scA[tid];
    int inc = own;
#pragma unroll
    for (int d = 1; d < 64; d <<= 1) {
        const int t = __shfl_up(inc, d);
        if (ln >= d) inc += t;
    }
    if (ln == 63) wsum[wv] = inc;
    __syncthreads();
    if (wv == 0) {
        int v = (ln < 16) ? wsum[ln] : 0;
#pragma unroll
        for (int d = 1; d < 16; d <<= 1) {
            const int t = __shfl_up(v, d);
            if (ln >= d) v += t;
        }
        if (ln < 16) wsum[ln] = v;      // inclusive wave sums
    }
    __syncthreads();
    const int wbase  = (wv == 0) ? 0 : wsum[wv - 1];
    const int myBase = wbase + inc - own;   // exclusive global base
    scB[tid] = myBase;
    __syncthreads();
    int* const bbase = scB;

    // --- phase 4: scatter + straddle-overflow check ---
    if (bk0 >= 0) { const int p = bbase[bk0] + r0; if (p < KEYS_MAX) keyS[p] = k0; }
    if (bk1 >= 0) { const int p = bbase[bk1] + r1; if (p < KEYS_MAX) keyS[p] = k1; }
    if (own > 0 && myBase < SCAN && myBase + own > KEYS_MAX) flagSh = 1;
    __syncthreads();

    // --- phase 5: per-bucket insertion sort (descending u64; ranks exact) ---
    {
        const int lo = myBase;
        const int hi = min(lo + own, KEYS_MAX);
        if (own >= 2 && lo < KEYS_MAX) {
            for (int a = lo + 1; a < hi; ++a) {
                const u64 kk = keyS[a];
                int p = a - 1;
                while (p >= lo && keyS[p] < kk) { keyS[p + 1] = keyS[p]; --p; }
                keyS[p + 1] = kk;
            }
        }
    }
    __syncthreads();

    // --- phase 6: gather boxes (packed) + areas ---
    if (tid < scanN) {
        const u64 kk = keyS[tid];
        const int n = (int)(0xFFFFFFFFu - (u32)kk);
        const float4 bx = *reinterpret_cast<const float4*>(boxb + (size_t)n * 4);
        sbox4[tid] = bx;
        sar[tid]   = (bx.z - bx.x) * (bx.w - bx.y);
    }
    __syncthreads();

    // --- phase 7: mask build — pinned j-cache, batched row loads, 1 write/row ---
    {
        float rjx1[8], rjy1[8], rjx2[8], rjy2[8], rja[8];
#pragma unroll
        for (int w = 0; w < 8; ++w) {
            const int j = w * 64 + ln;
            const float4 bj = sbox4[j];
            rjx1[w] = bj.x; rjy1[w] = bj.y; rjx2[w] = bj.z; rjy2[w] = bj.w;
            rja[w]  = sar[j];
            asm volatile("" : "+v"(rjx1[w]), "+v"(rjy1[w]), "+v"(rjx2[w]),
                              "+v"(rjy2[w]), "+v"(rja[w]));   // defeat LDS remat
        }
#pragma unroll
        for (int k8 = 0; k8 < 4; ++k8) {
            const int rbase = wv + 16 * (k8 * 8);   // rows rbase + 16r, r<8 (max 511)
            float4 bv = make_float4(0.f, 0.f, 0.f, 0.f);
            float  av = 0.f;
            if (ln < 8)       bv = sbox4[rbase + 16 * ln];          // 1 ds_read_b128
            else if (ln < 16) av = sar[rbase + 16 * (ln - 8)];      // 1 ds_read_b32
#pragma unroll
            for (int r = 0; r < 8; ++r) {
                const int i8 = rbase + 16 * r;
                const bool iv = (i8 < scanN);
                const float px1 = rdlane(bv.x, r);    // scalar broadcast, no LDS
                const float py1 = rdlane(bv.y, r);
                const float px2 = rdlane(bv.z, r);
                const float py2 = rdlane(bv.w, r);
                const float pa  = rdlane(av, 8 + r);
                const int wlo = i8 >> 6;              // diagonal word (wave-uniform)
                u64 bal[8] = {0, 0, 0, 0, 0, 0, 0, 0};
#pragma unroll
                for (int w = 0; w < 8; ++w) {
                    if (w >= wlo) {                   // wave-uniform skip (upper tri)
                        const int j = w * 64 + ln;
                        const bool jv = (j < scanN) && (j != i8);
                        const float ix1 = fmaxf(px1, rjx1[w]), iy1 = fmaxf(py1, rjy1[w]);
                        const float ix2 = fminf(px2, rjx2[w]), iy2 = fminf(py2, rjy2[w]);
                        const bool ov = iv && jv && (ix2 > ix1) && (iy2 > iy1);
                        bool sup = false;
                        if (__any(ov)) {
                            const float inter = fmaxf(ix2 - ix1, 0.f) * fmaxf(iy2 - iy1, 0.f);
                            const float iou = inter / (pa + rja[w] - inter + 1e-8f); // ref order
                            sup = ov && (iou > IOU_THR);
                        }
                        bal[w] = __ballot(sup);
                    }
                }
                u64 mv = bal[0];                      // static select chain
                if (ln == 1) mv = bal[1];
                if (ln == 2) mv = bal[2];
                if (ln == 3) mv = bal[3];
                if (ln == 4) mv = bal[4];
                if (ln == 5) mv = bal[5];
                if (ln == 6) mv = bal[6];
                if (ln == 7) mv = bal[7];
                if (ln < 8) mask[i8][ln] = mv;        // ONE ds_write_b64 per row
            }
        }
    }
    __syncthreads();

    // --- phase 8: chunked greedy resolve (wave 0) ---
    if (wv == 0) {
        u64 remv[8] = {0, 0, 0, 0, 0, 0, 0, 0};
        int cnt = 0;
#pragma unroll
        for (int c = 0; c < 8; ++c) {                   // full unroll: static remv[c]
            if (cnt < MAXDET) {
                const int i = c * 64 + ln;
                const bool valid = (i < scanN);
                u64 alive = __ballot(valid && !((remv[c] >> ln) & 1ULL));
                const u64 sub = valid ? mask[i][c] : 0ULL;   // my column == my row (sym)
                u64 keptM = 0ULL;
                const int cbase = cnt;
                while (alive) {
                    const int f = __ffsll((unsigned long long)alive) - 1;
                    keptM |= (1ULL << f);
                    ++cnt;
                    if (cnt >= MAXDET) break;
                    const bool meSup = ((sub >> f) & 1ULL) != 0ULL;
                    const u64 supM = __ballot(meSup);
                    alive &= ~(supM | (1ULL << f));
                }
                if ((keptM >> ln) & 1ULL) {
                    const int pos = cbase + __popcll(keptM & ((1ULL << ln) - 1ULL));
                    const u64 kk = keyS[i];
                    ksc[pos] = __uint_as_float((u32)(kk >> 32));
                    kix[pos] = (int)(0xFFFFFFFFu - (u32)kk);
                }
                if (cnt < MAXDET && c < 7) {            // propagate removals forward
#pragma unroll
                    for (int w = 0; w < 8; ++w) {
                        if (w > c) {                    // only future-chunk words
                            u64 x = ((keptM >> ln) & 1ULL) ? mask[c * 64 + ln][w] : 0ULL;
#pragma unroll
                            for (int m = 1; m < 64; m <<= 1)
                                x |= (u64)__shfl_xor((long long)x, m);
                            remv[w] |= x;
                        }
                    }
                }
            }
        }
        if (ln == 0) cntSh = cnt;
    }
    __syncthreads();

    // --- phase 9: write out ---
    const int cnt = cntSh;
    for (int k2 = tid; k2 < cnt; k2 += 1024) {
        keptIdx[bc * MAXDET + k2]   = kix[k2];
        keptScore[bc * MAXDET + k2] = ksc[k2];
    }
    if (tid == 0) {
        keptCnt[bc] = cnt;
        flagInc[bc] = (raw > CAP
                       || flagSh
                       || (cnt < MAXDET && totalCand[bc] > use)   // pool cut by T0
                       || (cnt < MAXDET && use > scanN)           // window exhausted
                      ) ? 1 : 0;
    }
}

// ==================== slow path (round-1, verified) ====================

__device__ __forceinline__ void combineMax(float& bs, int& bi, float os, int oi) {
    if (os > bs || (os == bs && oi < bi)) { bs = os; bi = oi; }
}

template<int NPT>
__global__ __launch_bounds__(BS) void nms_slow_kernel(
    const float* __restrict__ boxes, const float* __restrict__ cls,
    const float* __restrict__ cent, int B, int N, int C,
    int* __restrict__ keptIdx, float* __restrict__ keptScore, int* __restrict__ keptCnt,
    const int* __restrict__ flagInc)
{
    const int bc = blockIdx.x;
    if (flagInc != nullptr && flagInc[bc] == 0) return;   // fast path was complete
    const int b   = bc / C;
    const int c   = bc - b * C;
    const int tid = threadIdx.x;

    const float* __restrict__ clsb  = cls  + (size_t)b * N * C + c;
    const float* __restrict__ centb = cent + (size_t)b * N;
    const float* __restrict__ boxb  = boxes + (size_t)b * N * 4;

    float s[NPT];
#pragma unroll
    for (int j = 0; j < NPT; ++j) {
        int n = tid + j * BS;
        float v = -1.0f;
        if (n < N) {
            float cv = clsb[(size_t)n * C];
            if (cv > SCORE_THR) v = sqrtf(cv * centb[n]);
        }
        s[j] = v;
    }

    __shared__ float kx1[MAXDET], ky1[MAXDET], kx2[MAXDET], ky2[MAXDET];
    __shared__ float kscore[MAXDET];
    __shared__ int   kidx[MAXDET];
    __shared__ float redS[BS / 64];
    __shared__ int   redI[BS / 64];
    __shared__ float pbox[4];
    __shared__ float pscoreSh;
    __shared__ int   ctrl;
    __shared__ int   supFlag;

    const int lane = tid & 63;
    const int wid  = tid >> 6;
    const int NW   = BS / 64;
    int cnt = 0;

    const int maxIter = N + MAXDET + 2;
    for (int iter = 0; iter < maxIter; ++iter) {
        float bs = -1.0f; int bi = 0x7fffffff;
#pragma unroll
        for (int j = 0; j < NPT; ++j) {
            if (s[j] > bs) { bs = s[j]; bi = tid + j * BS; }
        }
        for (int m = 1; m < 64; m <<= 1) {
            float os = __shfl_xor(bs, m);
            int   oi = __shfl_xor(bi, m);
            combineMax(bs, bi, os, oi);
        }
        if (lane == 0) { redS[wid] = bs; redI[wid] = bi; }
        __syncthreads();
        if (tid == 0) {
            float gs = redS[0]; int gi = redI[0];
            for (int w = 1; w < NW; ++w) combineMax(gs, gi, redS[w], redI[w]);
            supFlag = 0;
            if (gs <= 0.0f) {
                ctrl = -1;
            } else {
                ctrl = gi; pscoreSh = gs;
                const float4 bx = *reinterpret_cast<const float4*>(boxb + (size_t)gi * 4);
                pbox[0] = bx.x; pbox[1] = bx.y; pbox[2] = bx.z; pbox[3] = bx.w;
            }
        }
        __syncthreads();
        const int P = ctrl;
        if (P < 0) break;

        if ((P & (BS - 1)) == tid) {
            const int jp = P >> 10;
#pragma unroll
            for (int j = 0; j < NPT; ++j) if (j == jp) s[j] = -1.0f;
        }

        if (tid < cnt) {
            const float px1 = pbox[0], py1 = pbox[1], px2 = pbox[2], py2 = pbox[3];
            const float qx1 = kx1[tid], qy1 = ky1[tid], qx2 = kx2[tid], qy2 = ky2[tid];
            const float ix1 = fmaxf(qx1, px1), iy1 = fmaxf(qy1, py1);
            const float ix2 = fminf(qx2, px2), iy2 = fminf(qy2, py2);
            const float inter = fmaxf(ix2 - ix1, 0.0f) * fmaxf(iy2 - iy1, 0.0f);
            const float aq = (qx2 - qx1) * (qy2 - qy1);
            const float ap = (px2 - px1) * (py2 - py1);
            const float iou = inter / (aq + ap - inter + 1e-8f);
            if (iou > IOU_THR) supFlag = 1;
        }
        __syncthreads();
        if (supFlag == 0) {
            if (tid == 0) {
                kx1[cnt] = pbox[0]; ky1[cnt] = pbox[1];
                kx2[cnt] = pbox[2]; ky2[cnt] = pbox[3];
                kscore[cnt] = pscoreSh; kidx[cnt] = P;
            }
            ++cnt;
            if (cnt == MAXDET) break;
        }
    }

    for (int k = tid; k < cnt; k += BS) {
        keptIdx[(size_t)bc * MAXDET + k]   = kidx[k];
        keptScore[(size_t)bc * MAXDET + k] = kscore[k];
    }
    if (tid == 0) keptCnt[bc] = cnt;
}

// ========== final top-300: bucket sort of C*300 kept keys (1 block/image) ==========
__global__ __launch_bounds__(1024) void topk_kernel(
    const float* __restrict__ boxes, const int* __restrict__ keptIdx,
    const float* __restrict__ keptScore, const int* __restrict__ keptCnt,
    int B, int N, int C, float* __restrict__ out)
{
    const int b   = blockIdx.x;
    const int tid = threadIdx.x;
    const int wv  = tid >> 6;
    const int ln  = tid & 63;

    __shared__ int cnts[16];
    __shared__ int cntA[NBUCK];
    __shared__ int bbS[NBUCK];
    __shared__ int wsum[16];
    __shared__ u64 sorted[16 * MAXDET];     // 37.5 KB
    __shared__ int totalSh;

    if (tid < 16) cnts[tid] = (tid < C) ? keptCnt[b * C + tid] : 0;
    cntA[tid] = 0;
    __syncthreads();
    if (tid == 0) {
        int t = 0;
        for (int c = 0; c < C; ++c) t += cnts[c];
        totalSh = t;
    }

    // load + bucket count (5 items/thread max: 16*300/1024 = 4.69)
    const int TOT = C * MAXDET;
    u64 mk[5]; int mb[5], mr[5];
#pragma unroll
    for (int t = 0; t < 5; ++t) {
        mb[t] = -1;
        const int i = tid + t * 1024;
        if (i < TOT) {
            const int c = i / MAXDET;
            const int k = i - c * MAXDET;
            if (k < cnts[c]) {
                const float sc = keptScore[(b * C + c) * MAXDET + k];
                const u32 fl = (u32)(c * N + keptIdx[(b * C + c) * MAXDET + k]);
                const u64 kk = ((u64)__float_as_uint(sc) << 32) | (0xFFFFFFFFu - fl);
                const u32 bits = (u32)(kk >> 32);
                const u32 d = bits > BITS_BASE ? bits - BITS_BASE : 0u;
                const int bk = (NBUCK - 1) - (int)min(d >> 11, (u32)(NBUCK - 1));
                mk[t] = kk; mb[t] = bk; mr[t] = atomicAdd(&cntA[bk], 1);
            }
        }
    }
    __syncthreads();

    // exclusive prefix over buckets (wave shfl-scan, 3 barriers)
    const int own = cntA[tid];
    int inc = own;
#pragma unroll
    for (int d = 1; d < 64; d <<= 1) {
        const int t = __shfl_up(inc, d);
        if (ln >= d) inc += t;
    }
    if (ln == 63) wsum[wv] = inc;
    __syncthreads();
    if (wv == 0) {
        int v = (ln < 16) ? wsum[ln] : 0;
#pragma unroll
        for (int d = 1; d < 16; d <<= 1) {
            const int t = __shfl_up(v, d);
            if (ln >= d) v += t;
        }
        if (ln < 16) wsum[ln] = v;
    }
    __syncthreads();
    const int wbase  = (wv == 0) ? 0 : wsum[wv - 1];
    const int myBase = wbase + inc - own;
    bbS[tid] = myBase;
    __syncthreads();

    // scatter
#pragma unroll
    for (int t = 0; t < 5; ++t)
        if (mb[t] >= 0) sorted[bbS[mb[t]] + mr[t]] = mk[t];
    __syncthreads();

    // per-bucket insertion sort (descending)
    {
        const int lo = myBase;
        const int hi = lo + own;
        if (own >= 2) {
            for (int a = lo + 1; a < hi; ++a) {
                const u64 kk = sorted[a];
                int p = a - 1;
                while (p >= lo && sorted[p] < kk) { sorted[p + 1] = sorted[p]; --p; }
                sorted[p + 1] = kk;
            }
        }
    }
    __syncthreads();

    // write top-300 directly
    const int total = totalSh;
    if (tid < MAXDET) {
        float4 bx = make_float4(-1.0f, -1.0f, -1.0f, -1.0f);
        float so = -1.0f, lo2 = -1.0f;
        if (tid < total) {
            const u64 kk = sorted[tid];
            so = __uint_as_float((u32)(kk >> 32));
            const int fl = (int)(0xFFFFFFFFu - (u32)kk);
            const int label  = fl / N;
            const int anchor = fl - label * N;
            bx = *reinterpret_cast<const float4*>(boxes + ((size_t)b * N + anchor) * 4);
            lo2 = (float)label;
        }
        *reinterpret_cast<float4*>(out + (size_t)(b * MAXDET + tid) * 4) = bx;
        out[(size_t)B * MAXDET * 4 + b * MAXDET + tid] = so;
        out[(size_t)B * MAXDET * 5 + b * MAXDET + tid] = lo2;
    }
}

// ============================ launcher ============================

extern "C" void kernel_launch(void* const* d_in, const int* in_sizes, int n_in,
                              void* d_out, int out_size, void* d_ws, size_t ws_size,
                              hipStream_t stream) {
    const float* boxes = (const float*)d_in[0];
    const float* cls   = (const float*)d_in[1];
    const float* cent  = (const float*)d_in[2];
    float* out = (float*)d_out;

    const int B = out_size / (MAXDET * 6);
    if (B <= 0) return;
    const int N = in_sizes[2] / B;
    const int C = in_sizes[1] / in_sizes[2];
    if (N <= 0 || C <= 0 || C > 16) return;
    const int BC = B * C;

    char* base = (char*)d_ws;
    size_t off = 0;
    int*   keptIdx   = (int*)(base + off);   off += (size_t)BC * MAXDET * sizeof(int);
    float* keptScore = (float*)(base + off); off += (size_t)BC * MAXDET * sizeof(float);
    int*   keptCnt   = (int*)(base + off);   off += (size_t)BC * sizeof(int);
    int*   flagInc   = (int*)(base + off);   off += (size_t)BC * sizeof(int);
    const size_t slowNeed = off;
    int*   cntRaw    = (int*)(base + off);   off += (size_t)BC * sizeof(int);
    int*   totalCand = (int*)(base + off);   off += (size_t)BC * sizeof(int);
    off = (off + 7) & ~(size_t)7;
    u64*   candPacked = (u64*)(base + off);  off += (size_t)BC * CAP * sizeof(u64);
    const size_t fastNeed = off;

    const int nptNeeded = (N + BS - 1) / BS;
    if (nptNeeded > 64) return;

    const bool fast = (C == 16) && (ws_size >= fastNeed);

    if (fast) {
        hipMemsetAsync(cntRaw, 0, 2 * (size_t)BC * sizeof(int), stream);
        score_compact_kernel<<<B * SPLIT, 256, 0, stream>>>(
            cls, cent, N, C, candPacked, cntRaw, totalCand);
        sort_nms_kernel<<<BC, 1024, 0, stream>>>(
            boxes, candPacked, cntRaw, totalCand, N, C,
            keptIdx, keptScore, keptCnt, flagInc);
        if (nptNeeded <= 49)
            nms_slow_kernel<49><<<BC, BS, 0, stream>>>(boxes, cls, cent, B, N, C,
                                                       keptIdx, keptScore, keptCnt, flagInc);
        else
            nms_slow_kernel<64><<<BC, BS, 0, stream>>>(boxes, cls, cent, B, N, C,
                                                       keptIdx, keptScore, keptCnt, flagInc);
    } else {
        if (ws_size < slowNeed) return;
        if (nptNeeded <= 49)
            nms_slow_kernel<49><<<BC, BS, 0, stream>>>(boxes, cls, cent, B, N, C,
                                                       keptIdx, keptScore, keptCnt, nullptr);
        else
            nms_slow_kernel<64><<<BC, BS, 0, stream>>>(boxes, cls, cent, B, N, C,
                                                       keptIdx, keptScore, keptCnt, nullptr);
    }

    topk_kernel<<<B, 1024, 0, stream>>>(boxes, keptIdx, keptScore, keptCnt, B, N, C, out);
}

// Round 14
// 136.643 us; speedup vs baseline: 1.1891x; 1.1891x over previous
//
#include <hip/hip_runtime.h>
#include <cstdint>
#include <cstddef>

#define MAXDET 300
#define IOU_THR 0.6f
#define SCORE_THR 0.05f
#define T0 0.9f          // combined-score compaction threshold (fallback-guarded)
#define CAP 2048         // per-class candidate capacity (expected ~1075)
#define SCAN 512         // NMS scan window over sorted candidates (examined ~345)
#define LCAP 64          // per-block per-class LDS list capacity in score pass
#define SPLIT 128        // blocks per image in score pass
#define BS 1024          // slow-path block size
#define NBUCK 1024       // bucket-sort bins
#define KEYS_MAX 576     // SCAN + slack for the straddling bucket
#define BITS_BASE 0x3F666666u   // float bits of 0.9f (fast-path scores >= 0.9)

typedef unsigned int u32;
typedef unsigned long long u64;

// ============================ fast path ============================

// Pass 1: coalesced score compute + LDS-aggregated per-class compaction.
__global__ __launch_bounds__(256) void score_compact_kernel(
    const float* __restrict__ cls, const float* __restrict__ cent,
    int N, int C,
    u64* __restrict__ candPacked, int* __restrict__ cntRaw, int* __restrict__ totalCand)
{
    const int b = blockIdx.x / SPLIT;
    const int s = blockIdx.x % SPLIT;
    const int chunk = (N + SPLIT - 1) / SPLIT;
    const int n0 = s * chunk;
    const int n1 = min(n0 + chunk, N);
    const int tid = threadIdx.x;
    const int q  = tid & 3;        // quarter-row: classes 4q..4q+3
    const int ar = tid >> 2;       // anchor offset within 64-anchor tile

    __shared__ int lcnt[16];
    __shared__ int ltot[16];
    __shared__ int lbase[16];
    __shared__ u64 lbuf[16][LCAP];

    if (tid < 16) { lcnt[tid] = 0; ltot[tid] = 0; }
    __syncthreads();

    int myTot[4] = {0, 0, 0, 0};
    for (int n = n0 + ar; n < n1; n += 64) {
        const float4 r = *reinterpret_cast<const float4*>(
            cls + ((size_t)b * N + n) * 16 + q * 4);
        const float ce = cent[(size_t)b * N + n];
        const float cv[4] = {r.x, r.y, r.z, r.w};
#pragma unroll
        for (int u = 0; u < 4; ++u) {
            const float v = cv[u];
            if (v > SCORE_THR) {
                myTot[u]++;
                const float prod = v * ce;
                if (prod >= 0.80f) {                       // conservative pre-filter
                    const float comb = sqrtf(prod);        // exact ref expression
                    if (comb >= T0) {
                        const int c = 4 * q + u;
                        const u64 key = ((u64)__float_as_uint(comb) << 32)
                                      | (u32)(0xFFFFFFFFu - (u32)n);  // score desc, n asc
                        const int lp = atomicAdd(&lcnt[c], 1);
                        if (lp < LCAP) {
                            lbuf[c][lp] = key;
                        } else {  // overflow (astronomically rare): direct append
                            const int pos = atomicAdd(&cntRaw[b * 16 + c], 1);
                            if (pos < CAP)
                                candPacked[((size_t)(b * 16 + c) << 11) + pos] = key;
                        }
                    }
                }
            }
        }
    }
#pragma unroll
    for (int u = 0; u < 4; ++u) atomicAdd(&ltot[4 * q + u], myTot[u]);
    __syncthreads();

    if (tid < 16) {
        const int m = min(lcnt[tid], LCAP);
        lbase[tid] = atomicAdd(&cntRaw[b * 16 + tid], m);   // reserve range
        atomicAdd(&totalCand[b * 16 + tid], ltot[tid]);
    }
    __syncthreads();

    for (int idx = tid; idx < 16 * LCAP; idx += 256) {      // coalesced flush
        const int c = idx >> 6;            // LCAP == 64
        const int k = idx & 63;
        if (k < min(lcnt[c], LCAP)) {
            const int pos = lbase[c] + k;
            if (pos < CAP)
                candPacked[((size_t)(b * 16 + c) << 11) + pos] = lbuf[c][k];
        }
    }
}

// Pass 2 (fused bucket-sort + mask + chunked NMS), one 1024-thread block per (b,c).
// ROUND-14 = round-12 verified code + ONE change: asm-pin the 40 j-cache
// floats ("+v") so the compiler cannot rematerialize them from LDS per use
// (round-12's 63.5us was dominated by ~20k hidden remat LDS reads/wave).
// NO bal[] array (round-13 lesson: PromoteAlloca moved it to LDS ->
// LDS 62464->128000, bank conflicts 36.8k->11.5M, 63.5->90.5us).
// Guards: LDS_Block_Size must stay 62464; WRITE_SIZE ~312KB.
__global__ __launch_bounds__(1024)
__attribute__((amdgpu_waves_per_eu(4, 4)))
void sort_nms_kernel(
    const float* __restrict__ boxes, const u64* __restrict__ candPacked,
    const int* __restrict__ cntRaw, const int* __restrict__ totalCand,
    int N, int C,
    int* __restrict__ keptIdx, float* __restrict__ keptScore,
    int* __restrict__ keptCnt, int* __restrict__ flagInc)
{
    const int bc  = blockIdx.x;
    const int b   = bc / C;
    const int tid = threadIdx.x;
    const int wv  = tid >> 6;
    const int ln  = tid & 63;
    const int raw = cntRaw[bc];
    const int use = min(raw, CAP);
    const int scanN = min(use, SCAN);
    const float* __restrict__ boxb = boxes + (size_t)b * N * 4;
    const u64* __restrict__ gbase = candPacked + ((size_t)bc << 11);

    __shared__ u64    keyS[KEYS_MAX];      // 4.5 KB sorted keys
    __shared__ float4 sbox4[SCAN];         // 8 KB packed boxes
    __shared__ float  sar[SCAN];           // 2 KB areas
    __shared__ int    scA[NBUCK];          // 4 KB bucket counts
    __shared__ int    scB[NBUCK];          // 4 KB exclusive bases
    __shared__ int    wsum[16];
    __shared__ u64    mask[SCAN][9];       // 36 KB (pad 9 vs 8)
    __shared__ float  ksc[MAXDET];
    __shared__ int    kix[MAXDET];
    __shared__ int    cntSh, flagSh;

    // --- phase 1: zero ---
    scA[tid] = 0;
    if (tid == 0) flagSh = 0;
    __syncthreads();

    // --- phase 2: load + bucket count (2 items/thread, coalesced) ---
    u64 k0 = 0, k1 = 0; int bk0 = -1, bk1 = -1, r0 = 0, r1 = 0;
    if (tid < use) {
        k0 = gbase[tid];
        const u32 bits = (u32)(k0 >> 32);
        const u32 d = bits > BITS_BASE ? bits - BITS_BASE : 0u;
        bk0 = (NBUCK - 1) - (int)min(d >> 11, (u32)(NBUCK - 1));   // high score -> low bucket
        r0 = atomicAdd(&scA[bk0], 1);
    }
    if (tid + 1024 < use) {
        k1 = gbase[tid + 1024];
        const u32 bits = (u32)(k1 >> 32);
        const u32 d = bits > BITS_BASE ? bits - BITS_BASE : 0u;
        bk1 = (NBUCK - 1) - (int)min(d >> 11, (u32)(NBUCK - 1));
        r1 = atomicAdd(&scA[bk1], 1);
    }
    __syncthreads();

    // --- phase 3: exclusive prefix over buckets (wave shfl-scan, 3 barriers) ---
    const int own = scA[tid];
    int inc = own;
#pragma unroll
    for (int d = 1; d < 64; d <<= 1) {
        const int t = __shfl_up(inc, d);
        if (ln >= d) inc += t;
    }
    if (ln == 63) wsum[wv] = inc;
    __syncthreads();
    if (wv == 0) {
        int v = (ln < 16) ? wsum[ln] : 0;
#pragma unroll
        for (int d = 1; d < 16; d <<= 1) {
            const int t = __shfl_up(v, d);
            if (ln >= d) v += t;
        }
        if (ln < 16) wsum[ln] = v;      // inclusive wave sums
    }
    __syncthreads();
    const int wbase  = (wv == 0) ? 0 : wsum[wv - 1];
    const int myBase = wbase + inc - own;   // exclusive global base
    scB[tid] = myBase;
    __syncthreads();
    int* const bbase = scB;

    // --- phase 4: scatter + straddle-overflow check ---
    if (bk0 >= 0) { const int p = bbase[bk0] + r0; if (p < KEYS_MAX) keyS[p] = k0; }
    if (bk1 >= 0) { const int p = bbase[bk1] + r1; if (p < KEYS_MAX) keyS[p] = k1; }
    if (own > 0 && myBase < SCAN && myBase + own > KEYS_MAX) flagSh = 1;
    __syncthreads();

    // --- phase 5: per-bucket insertion sort (descending u64; ranks exact) ---
    {
        const int lo = myBase;
        const int hi = min(lo + own, KEYS_MAX);
        if (own >= 2 && lo < KEYS_MAX) {
            for (int a = lo + 1; a < hi; ++a) {
                const u64 kk = keyS[a];
                int p = a - 1;
                while (p >= lo && keyS[p] < kk) { keyS[p + 1] = keyS[p]; --p; }
                keyS[p + 1] = kk;
            }
        }
    }
    __syncthreads();

    // --- phase 6: gather boxes (packed) + areas ---
    if (tid < scanN) {
        const u64 kk = keyS[tid];
        const int n = (int)(0xFFFFFFFFu - (u32)kk);
        const float4 bx = *reinterpret_cast<const float4*>(boxb + (size_t)n * 4);
        sbox4[tid] = bx;
        sar[tid]   = (bx.z - bx.x) * (bx.w - bx.y);
    }
    __syncthreads();

    // --- phase 7: mask build — asm-pinned register j-cache (defeat LDS remat) ---
    {
        float rjx1[8], rjy1[8], rjx2[8], rjy2[8], rja[8];
#pragma unroll
        for (int w = 0; w < 8; ++w) {
            const int j = w * 64 + ln;
            const float4 bj = sbox4[j];
            rjx1[w] = bj.x; rjy1[w] = bj.y; rjx2[w] = bj.z; rjy2[w] = bj.w;
            rja[w]  = sar[j];
            asm volatile("" : "+v"(rjx1[w]), "+v"(rjy1[w]), "+v"(rjx2[w]),
                              "+v"(rjy2[w]), "+v"(rja[w]));   // pin: no LDS remat
        }
        for (int i = wv; i < scanN; i += 16) {
            const float4 bp = sbox4[i];                  // 1 broadcast b128
            const float pa = sar[i];                     // 1 broadcast b32
            const int wlo = i >> 6;                      // diagonal word
#pragma unroll
            for (int w = 0; w < 8; ++w) {
                if (w >= wlo) {                          // wave-uniform skip (upper tri)
                    const int j = w * 64 + ln;
                    const bool jv = (j < scanN) && (j != i);
                    const float ix1 = fmaxf(bp.x, rjx1[w]), iy1 = fmaxf(bp.y, rjy1[w]);
                    const float ix2 = fminf(bp.z, rjx2[w]), iy2 = fminf(bp.w, rjy2[w]);
                    const bool ov = jv && (ix2 > ix1) && (iy2 > iy1);
                    bool sup = false;
                    if (__any(ov)) {
                        const float inter = fmaxf(ix2 - ix1, 0.f) * fmaxf(iy2 - iy1, 0.f);
                        const float iou = inter / (pa + rja[w] - inter + 1e-8f); // ref order
                        sup = ov && (iou > IOU_THR);
                    }
                    const u64 bal = __ballot(sup);       // one live ballot at a time
                    if (ln == 0) mask[i][w] = bal;
                }
            }
        }
    }
    __syncthreads();

    // --- phase 8: chunked greedy resolve (wave 0) ---
    if (wv == 0) {
        u64 remv[8] = {0, 0, 0, 0, 0, 0, 0, 0};
        int cnt = 0;
#pragma unroll
        for (int c = 0; c < 8; ++c) {                   // full unroll: static remv[c]
            if (cnt < MAXDET) {
                const int i = c * 64 + ln;
                const bool valid = (i < scanN);
                u64 alive = __ballot(valid && !((remv[c] >> ln) & 1ULL));
                const u64 sub = valid ? mask[i][c] : 0ULL;   // my column == my row (sym)
                u64 keptM = 0ULL;
                const int cbase = cnt;
                while (alive) {
                    const int f = __ffsll((unsigned long long)alive) - 1;
                    keptM |= (1ULL << f);
                    ++cnt;
                    if (cnt >= MAXDET) break;
                    const bool meSup = ((sub >> f) & 1ULL) != 0ULL;
                    const u64 supM = __ballot(meSup);
                    alive &= ~(supM | (1ULL << f));
                }
                if ((keptM >> ln) & 1ULL) {
                    const int pos = cbase + __popcll(keptM & ((1ULL << ln) - 1ULL));
                    const u64 kk = keyS[i];
                    ksc[pos] = __uint_as_float((u32)(kk >> 32));
                    kix[pos] = (int)(0xFFFFFFFFu - (u32)kk);
                }
                if (cnt < MAXDET && c < 7) {            // propagate removals forward
#pragma unroll
                    for (int w = 0; w < 8; ++w) {
                        if (w > c) {                    // only future-chunk words
                            u64 x = ((keptM >> ln) & 1ULL) ? mask[c * 64 + ln][w] : 0ULL;
#pragma unroll
                            for (int m = 1; m < 64; m <<= 1)
                                x |= (u64)__shfl_xor((long long)x, m);
                            remv[w] |= x;
                        }
                    }
                }
            }
        }
        if (ln == 0) cntSh = cnt;
    }
    __syncthreads();

    // --- phase 9: write out ---
    const int cnt = cntSh;
    for (int k2 = tid; k2 < cnt; k2 += 1024) {
        keptIdx[bc * MAXDET + k2]   = kix[k2];
        keptScore[bc * MAXDET + k2] = ksc[k2];
    }
    if (tid == 0) {
        keptCnt[bc] = cnt;
        flagInc[bc] = (raw > CAP
                       || flagSh
                       || (cnt < MAXDET && totalCand[bc] > use)   // pool cut by T0
                       || (cnt < MAXDET && use > scanN)           // window exhausted
                      ) ? 1 : 0;
    }
}

// ==================== slow path (round-1, verified) ====================

__device__ __forceinline__ void combineMax(float& bs, int& bi, float os, int oi) {
    if (os > bs || (os == bs && oi < bi)) { bs = os; bi = oi; }
}

template<int NPT>
__global__ __launch_bounds__(BS) void nms_slow_kernel(
    const float* __restrict__ boxes, const float* __restrict__ cls,
    const float* __restrict__ cent, int B, int N, int C,
    int* __restrict__ keptIdx, float* __restrict__ keptScore, int* __restrict__ keptCnt,
    const int* __restrict__ flagInc)
{
    const int bc = blockIdx.x;
    if (flagInc != nullptr && flagInc[bc] == 0) return;   // fast path was complete
    const int b   = bc / C;
    const int c   = bc - b * C;
    const int tid = threadIdx.x;

    const float* __restrict__ clsb  = cls  + (size_t)b * N * C + c;
    const float* __restrict__ centb = cent + (size_t)b * N;
    const float* __restrict__ boxb  = boxes + (size_t)b * N * 4;

    float s[NPT];
#pragma unroll
    for (int j = 0; j < NPT; ++j) {
        int n = tid + j * BS;
        float v = -1.0f;
        if (n < N) {
            float cv = clsb[(size_t)n * C];
            if (cv > SCORE_THR) v = sqrtf(cv * centb[n]);
        }
        s[j] = v;
    }

    __shared__ float kx1[MAXDET], ky1[MAXDET], kx2[MAXDET], ky2[MAXDET];
    __shared__ float kscore[MAXDET];
    __shared__ int   kidx[MAXDET];
    __shared__ float redS[BS / 64];
    __shared__ int   redI[BS / 64];
    __shared__ float pbox[4];
    __shared__ float pscoreSh;
    __shared__ int   ctrl;
    __shared__ int   supFlag;

    const int lane = tid & 63;
    const int wid  = tid >> 6;
    const int NW   = BS / 64;
    int cnt = 0;

    const int maxIter = N + MAXDET + 2;
    for (int iter = 0; iter < maxIter; ++iter) {
        float bs = -1.0f; int bi = 0x7fffffff;
#pragma unroll
        for (int j = 0; j < NPT; ++j) {
            if (s[j] > bs) { bs = s[j]; bi = tid + j * BS; }
        }
        for (int m = 1; m < 64; m <<= 1) {
            float os = __shfl_xor(bs, m);
            int   oi = __shfl_xor(bi, m);
            combineMax(bs, bi, os, oi);
        }
        if (lane == 0) { redS[wid] = bs; redI[wid] = bi; }
        __syncthreads();
        if (tid == 0) {
            float gs = redS[0]; int gi = redI[0];
            for (int w = 1; w < NW; ++w) combineMax(gs, gi, redS[w], redI[w]);
            supFlag = 0;
            if (gs <= 0.0f) {
                ctrl = -1;
            } else {
                ctrl = gi; pscoreSh = gs;
                const float4 bx = *reinterpret_cast<const float4*>(boxb + (size_t)gi * 4);
                pbox[0] = bx.x; pbox[1] = bx.y; pbox[2] = bx.z; pbox[3] = bx.w;
            }
        }
        __syncthreads();
        const int P = ctrl;
        if (P < 0) break;

        if ((P & (BS - 1)) == tid) {
            const int jp = P >> 10;
#pragma unroll
            for (int j = 0; j < NPT; ++j) if (j == jp) s[j] = -1.0f;
        }

        if (tid < cnt) {
            const float px1 = pbox[0], py1 = pbox[1], px2 = pbox[2], py2 = pbox[3];
            const float qx1 = kx1[tid], qy1 = ky1[tid], qx2 = kx2[tid], qy2 = ky2[tid];
            const float ix1 = fmaxf(qx1, px1), iy1 = fmaxf(qy1, py1);
            const float ix2 = fminf(qx2, px2), iy2 = fminf(qy2, py2);
            const float inter = fmaxf(ix2 - ix1, 0.0f) * fmaxf(iy2 - iy1, 0.0f);
            const float aq = (qx2 - qx1) * (qy2 - qy1);
            const float ap = (px2 - px1) * (py2 - py1);
            const float iou = inter / (aq + ap - inter + 1e-8f);
            if (iou > IOU_THR) supFlag = 1;
        }
        __syncthreads();
        if (supFlag == 0) {
            if (tid == 0) {
                kx1[cnt] = pbox[0]; ky1[cnt] = pbox[1];
                kx2[cnt] = pbox[2]; ky2[cnt] = pbox[3];
                kscore[cnt] = pscoreSh; kidx[cnt] = P;
            }
            ++cnt;
            if (cnt == MAXDET) break;
        }
    }

    for (int k = tid; k < cnt; k += BS) {
        keptIdx[(size_t)bc * MAXDET + k]   = kidx[k];
        keptScore[(size_t)bc * MAXDET + k] = kscore[k];
    }
    if (tid == 0) keptCnt[bc] = cnt;
}

// ========== final top-300: bucket sort of C*300 kept keys (1 block/image) ==========
__global__ __launch_bounds__(1024) void topk_kernel(
    const float* __restrict__ boxes, const int* __restrict__ keptIdx,
    const float* __restrict__ keptScore, const int* __restrict__ keptCnt,
    int B, int N, int C, float* __restrict__ out)
{
    const int b   = blockIdx.x;
    const int tid = threadIdx.x;
    const int wv  = tid >> 6;
    const int ln  = tid & 63;

    __shared__ int cnts[16];
    __shared__ int cntA[NBUCK];
    __shared__ int bbS[NBUCK];
    __shared__ int wsum[16];
    __shared__ u64 sorted[16 * MAXDET];     // 37.5 KB
    __shared__ int totalSh;

    if (tid < 16) cnts[tid] = (tid < C) ? keptCnt[b * C + tid] : 0;
    cntA[tid] = 0;
    __syncthreads();
    if (tid == 0) {
        int t = 0;
        for (int c = 0; c < C; ++c) t += cnts[c];
        totalSh = t;
    }

    // load + bucket count (5 items/thread max: 16*300/1024 = 4.69)
    const int TOT = C * MAXDET;
    u64 mk[5]; int mb[5], mr[5];
#pragma unroll
    for (int t = 0; t < 5; ++t) {
        mb[t] = -1;
        const int i = tid + t * 1024;
        if (i < TOT) {
            const int c = i / MAXDET;
            const int k = i - c * MAXDET;
            if (k < cnts[c]) {
                const float sc = keptScore[(b * C + c) * MAXDET + k];
                const u32 fl = (u32)(c * N + keptIdx[(b * C + c) * MAXDET + k]);
                const u64 kk = ((u64)__float_as_uint(sc) << 32) | (0xFFFFFFFFu - fl);
                const u32 bits = (u32)(kk >> 32);
                const u32 d = bits > BITS_BASE ? bits - BITS_BASE : 0u;
                const int bk = (NBUCK - 1) - (int)min(d >> 11, (u32)(NBUCK - 1));
                mk[t] = kk; mb[t] = bk; mr[t] = atomicAdd(&cntA[bk], 1);
            }
        }
    }
    __syncthreads();

    // exclusive prefix over buckets (wave shfl-scan, 3 barriers)
    const int own = cntA[tid];
    int inc = own;
#pragma unroll
    for (int d = 1; d < 64; d <<= 1) {
        const int t = __shfl_up(inc, d);
        if (ln >= d) inc += t;
    }
    if (ln == 63) wsum[wv] = inc;
    __syncthreads();
    if (wv == 0) {
        int v = (ln < 16) ? wsum[ln] : 0;
#pragma unroll
        for (int d = 1; d < 16; d <<= 1) {
            const int t = __shfl_up(v, d);
            if (ln >= d) v += t;
        }
        if (ln < 16) wsum[ln] = v;
    }
    __syncthreads();
    const int wbase  = (wv == 0) ? 0 : wsum[wv - 1];
    const int myBase = wbase + inc - own;
    bbS[tid] = myBase;
    __syncthreads();

    // scatter
#pragma unroll
    for (int t = 0; t < 5; ++t)
        if (mb[t] >= 0) sorted[bbS[mb[t]] + mr[t]] = mk[t];
    __syncthreads();

    // per-bucket insertion sort (descending)
    {
        const int lo = myBase;
        const int hi = lo + own;
        if (own >= 2) {
            for (int a = lo + 1; a < hi; ++a) {
                const u64 kk = sorted[a];
                int p = a - 1;
                while (p >= lo && sorted[p] < kk) { sorted[p + 1] = sorted[p]; --p; }
                sorted[p + 1] = kk;
            }
        }
    }
    __syncthreads();

    // write top-300 directly
    const int total = totalSh;
    if (tid < MAXDET) {
        float4 bx = make_float4(-1.0f, -1.0f, -1.0f, -1.0f);
        float so = -1.0f, lo2 = -1.0f;
        if (tid < total) {
            const u64 kk = sorted[tid];
            so = __uint_as_float((u32)(kk >> 32));
            const int fl = (int)(0xFFFFFFFFu - (u32)kk);
            const int label  = fl / N;
            const int anchor = fl - label * N;
            bx = *reinterpret_cast<const float4*>(boxes + ((size_t)b * N + anchor) * 4);
            lo2 = (float)label;
        }
        *reinterpret_cast<float4*>(out + (size_t)(b * MAXDET + tid) * 4) = bx;
        out[(size_t)B * MAXDET * 4 + b * MAXDET + tid] = so;
        out[(size_t)B * MAXDET * 5 + b * MAXDET + tid] = lo2;
    }
}

// ============================ launcher ============================

extern "C" void kernel_launch(void* const* d_in, const int* in_sizes, int n_in,
                              void* d_out, int out_size, void* d_ws, size_t ws_size,
                              hipStream_t stream) {
    const float* boxes = (const float*)d_in[0];
    const float* cls   = (const float*)d_in[1];
    const float* cent  = (const float*)d_in[2];
    float* out = (float*)d_out;

    const int B = out_size / (MAXDET * 6);
    if (B <= 0) return;
    const int N = in_sizes[2] / B;
    const int C = in_sizes[1] / in_sizes[2];
    if (N <= 0 || C <= 0 || C > 16) return;
    const int BC = B * C;

    char* base = (char*)d_ws;
    size_t off = 0;
    int*   keptIdx   = (int*)(base + off);   off += (size_t)BC * MAXDET * sizeof(int);
    float* keptScore = (float*)(base + off); off += (size_t)BC * MAXDET * sizeof(float);
    int*   keptCnt   = (int*)(base + off);   off += (size_t)BC * sizeof(int);
    int*   flagInc   = (int*)(base + off);   off += (size_t)BC * sizeof(int);
    const size_t slowNeed = off;
    int*   cntRaw    = (int*)(base + off);   off += (size_t)BC * sizeof(int);
    int*   totalCand = (int*)(base + off);   off += (size_t)BC * sizeof(int);
    off = (off + 7) & ~(size_t)7;
    u64*   candPacked = (u64*)(base + off);  off += (size_t)BC * CAP * sizeof(u64);
    const size_t fastNeed = off;

    const int nptNeeded = (N + BS - 1) / BS;
    if (nptNeeded > 64) return;

    const bool fast = (C == 16) && (ws_size >= fastNeed);

    if (fast) {
        hipMemsetAsync(cntRaw, 0, 2 * (size_t)BC * sizeof(int), stream);
        score_compact_kernel<<<B * SPLIT, 256, 0, stream>>>(
            cls, cent, N, C, candPacked, cntRaw, totalCand);
        sort_nms_kernel<<<BC, 1024, 0, stream>>>(
            boxes, candPacked, cntRaw, totalCand, N, C,
            keptIdx, keptScore, keptCnt, flagInc);
        if (nptNeeded <= 49)
            nms_slow_kernel<49><<<BC, BS, 0, stream>>>(boxes, cls, cent, B, N, C,
                                                       keptIdx, keptScore, keptCnt, flagInc);
        else
            nms_slow_kernel<64><<<BC, BS, 0, stream>>>(boxes, cls, cent, B, N, C,
                                                       keptIdx, keptScore, keptCnt, flagInc);
    } else {
        if (ws_size < slowNeed) return;
        if (nptNeeded <= 49)
            nms_slow_kernel<49><<<BC, BS, 0, stream>>>(boxes, cls, cent, B, N, C,
                                                       keptIdx, keptScore, keptCnt, nullptr);
        else
            nms_slow_kernel<64><<<BC, BS, 0, stream>>>(boxes, cls, cent, B, N, C,
                                                       keptIdx, keptScore, keptCnt, nullptr);
    }

    topk_kernel<<<B, 1024, 0, stream>>>(boxes, keptIdx, keptScore, keptCnt, B, N, C, out);
}

// Round 15
// 106.496 us; speedup vs baseline: 1.5257x; 1.2831x over previous
//
#include <hip/hip_runtime.h>
#include <cstdint>
#include <cstddef>

#define MAXDET 300
#define IOU_THR 0.6f
#define SCORE_THR 0.05f
#define T0 0.9f          // combined-score compaction threshold (fallback-guarded)
#define CAP 2048         // per-class candidate capacity (expected ~1075)
#define SCAN 512         // NMS scan window over sorted candidates (examined ~345)
#define LCAP 64          // per-block per-class LDS list capacity in score pass
#define SPLIT 128        // blocks per image in score pass
#define BS 1024          // slow-path block size
#define NBUCK 1024       // bucket-sort bins
#define KEYS_MAX 576     // SCAN + slack for the straddling bucket
#define BITS_BASE 0x3F666666u   // float bits of 0.9f (fast-path scores >= 0.9)

typedef unsigned int u32;
typedef unsigned long long u64;

// ============================ fast path ============================

// Pass 1: coalesced score compute + LDS-aggregated per-class compaction.
__global__ __launch_bounds__(256) void score_compact_kernel(
    const float* __restrict__ cls, const float* __restrict__ cent,
    int N, int C,
    u64* __restrict__ candPacked, int* __restrict__ cntRaw, int* __restrict__ totalCand)
{
    const int b = blockIdx.x / SPLIT;
    const int s = blockIdx.x % SPLIT;
    const int chunk = (N + SPLIT - 1) / SPLIT;
    const int n0 = s * chunk;
    const int n1 = min(n0 + chunk, N);
    const int tid = threadIdx.x;
    const int q  = tid & 3;        // quarter-row: classes 4q..4q+3
    const int ar = tid >> 2;       // anchor offset within 64-anchor tile

    __shared__ int lcnt[16];
    __shared__ int ltot[16];
    __shared__ int lbase[16];
    __shared__ u64 lbuf[16][LCAP];

    if (tid < 16) { lcnt[tid] = 0; ltot[tid] = 0; }
    __syncthreads();

    int myTot[4] = {0, 0, 0, 0};
    for (int n = n0 + ar; n < n1; n += 64) {
        const float4 r = *reinterpret_cast<const float4*>(
            cls + ((size_t)b * N + n) * 16 + q * 4);
        const float ce = cent[(size_t)b * N + n];
        const float cv[4] = {r.x, r.y, r.z, r.w};
#pragma unroll
        for (int u = 0; u < 4; ++u) {
            const float v = cv[u];
            if (v > SCORE_THR) {
                myTot[u]++;
                const float prod = v * ce;
                if (prod >= 0.80f) {                       // conservative pre-filter
                    const float comb = sqrtf(prod);        // exact ref expression
                    if (comb >= T0) {
                        const int c = 4 * q + u;
                        const u64 key = ((u64)__float_as_uint(comb) << 32)
                                      | (u32)(0xFFFFFFFFu - (u32)n);  // score desc, n asc
                        const int lp = atomicAdd(&lcnt[c], 1);
                        if (lp < LCAP) {
                            lbuf[c][lp] = key;
                        } else {  // overflow (astronomically rare): direct append
                            const int pos = atomicAdd(&cntRaw[b * 16 + c], 1);
                            if (pos < CAP)
                                candPacked[((size_t)(b * 16 + c) << 11) + pos] = key;
                        }
                    }
                }
            }
        }
    }
#pragma unroll
    for (int u = 0; u < 4; ++u) atomicAdd(&ltot[4 * q + u], myTot[u]);
    __syncthreads();

    if (tid < 16) {
        const int m = min(lcnt[tid], LCAP);
        lbase[tid] = atomicAdd(&cntRaw[b * 16 + tid], m);   // reserve range
        atomicAdd(&totalCand[b * 16 + tid], ltot[tid]);
    }
    __syncthreads();

    for (int idx = tid; idx < 16 * LCAP; idx += 256) {      // coalesced flush
        const int c = idx >> 6;            // LCAP == 64
        const int k = idx & 63;
        if (k < min(lcnt[c], LCAP)) {
            const int pos = lbase[c] + k;
            if (pos < CAP)
                candPacked[((size_t)(b * 16 + c) << 11) + pos] = lbuf[c][k];
        }
    }
}

// Pass 2 (fused bucket-sort + mask + chunked NMS), one 1024-thread block per (b,c).
// UNCHANGED from round 14 (verified 63.6us, absmax 0.0).
// Guards: LDS_Block_Size 62464; WRITE_SIZE ~312KB; dur 63.5 +- 1.
__global__ __launch_bounds__(1024)
__attribute__((amdgpu_waves_per_eu(4, 4)))
void sort_nms_kernel(
    const float* __restrict__ boxes, const u64* __restrict__ candPacked,
    const int* __restrict__ cntRaw, const int* __restrict__ totalCand,
    int N, int C,
    int* __restrict__ keptIdx, float* __restrict__ keptScore,
    int* __restrict__ keptCnt, int* __restrict__ flagInc)
{
    const int bc  = blockIdx.x;
    const int b   = bc / C;
    const int tid = threadIdx.x;
    const int wv  = tid >> 6;
    const int ln  = tid & 63;
    const int raw = cntRaw[bc];
    const int use = min(raw, CAP);
    const int scanN = min(use, SCAN);
    const float* __restrict__ boxb = boxes + (size_t)b * N * 4;
    const u64* __restrict__ gbase = candPacked + ((size_t)bc << 11);

    __shared__ u64    keyS[KEYS_MAX];      // 4.5 KB sorted keys
    __shared__ float4 sbox4[SCAN];         // 8 KB packed boxes
    __shared__ float  sar[SCAN];           // 2 KB areas
    __shared__ int    scA[NBUCK];          // 4 KB bucket counts
    __shared__ int    scB[NBUCK];          // 4 KB exclusive bases
    __shared__ int    wsum[16];
    __shared__ u64    mask[SCAN][9];       // 36 KB (pad 9 vs 8)
    __shared__ float  ksc[MAXDET];
    __shared__ int    kix[MAXDET];
    __shared__ int    cntSh, flagSh;

    // --- phase 1: zero ---
    scA[tid] = 0;
    if (tid == 0) flagSh = 0;
    __syncthreads();

    // --- phase 2: load + bucket count (2 items/thread, coalesced) ---
    u64 k0 = 0, k1 = 0; int bk0 = -1, bk1 = -1, r0 = 0, r1 = 0;
    if (tid < use) {
        k0 = gbase[tid];
        const u32 bits = (u32)(k0 >> 32);
        const u32 d = bits > BITS_BASE ? bits - BITS_BASE : 0u;
        bk0 = (NBUCK - 1) - (int)min(d >> 11, (u32)(NBUCK - 1));   // high score -> low bucket
        r0 = atomicAdd(&scA[bk0], 1);
    }
    if (tid + 1024 < use) {
        k1 = gbase[tid + 1024];
        const u32 bits = (u32)(k1 >> 32);
        const u32 d = bits > BITS_BASE ? bits - BITS_BASE : 0u;
        bk1 = (NBUCK - 1) - (int)min(d >> 11, (u32)(NBUCK - 1));
        r1 = atomicAdd(&scA[bk1], 1);
    }
    __syncthreads();

    // --- phase 3: exclusive prefix over buckets (wave shfl-scan, 3 barriers) ---
    const int own = scA[tid];
    int inc = own;
#pragma unroll
    for (int d = 1; d < 64; d <<= 1) {
        const int t = __shfl_up(inc, d);
        if (ln >= d) inc += t;
    }
    if (ln == 63) wsum[wv] = inc;
    __syncthreads();
    if (wv == 0) {
        int v = (ln < 16) ? wsum[ln] : 0;
#pragma unroll
        for (int d = 1; d < 16; d <<= 1) {
            const int t = __shfl_up(v, d);
            if (ln >= d) v += t;
        }
        if (ln < 16) wsum[ln] = v;      // inclusive wave sums
    }
    __syncthreads();
    const int wbase  = (wv == 0) ? 0 : wsum[wv - 1];
    const int myBase = wbase + inc - own;   // exclusive global base
    scB[tid] = myBase;
    __syncthreads();
    int* const bbase = scB;

    // --- phase 4: scatter + straddle-overflow check ---
    if (bk0 >= 0) { const int p = bbase[bk0] + r0; if (p < KEYS_MAX) keyS[p] = k0; }
    if (bk1 >= 0) { const int p = bbase[bk1] + r1; if (p < KEYS_MAX) keyS[p] = k1; }
    if (own > 0 && myBase < SCAN && myBase + own > KEYS_MAX) flagSh = 1;
    __syncthreads();

    // --- phase 5: per-bucket insertion sort (descending u64; ranks exact) ---
    {
        const int lo = myBase;
        const int hi = min(lo + own, KEYS_MAX);
        if (own >= 2 && lo < KEYS_MAX) {
            for (int a = lo + 1; a < hi; ++a) {
                const u64 kk = keyS[a];
                int p = a - 1;
                while (p >= lo && keyS[p] < kk) { keyS[p + 1] = keyS[p]; --p; }
                keyS[p + 1] = kk;
            }
        }
    }
    __syncthreads();

    // --- phase 6: gather boxes (packed) + areas ---
    if (tid < scanN) {
        const u64 kk = keyS[tid];
        const int n = (int)(0xFFFFFFFFu - (u32)kk);
        const float4 bx = *reinterpret_cast<const float4*>(boxb + (size_t)n * 4);
        sbox4[tid] = bx;
        sar[tid]   = (bx.z - bx.x) * (bx.w - bx.y);
    }
    __syncthreads();

    // --- phase 7: mask build — asm-pinned register j-cache ---
    {
        float rjx1[8], rjy1[8], rjx2[8], rjy2[8], rja[8];
#pragma unroll
        for (int w = 0; w < 8; ++w) {
            const int j = w * 64 + ln;
            const float4 bj = sbox4[j];
            rjx1[w] = bj.x; rjy1[w] = bj.y; rjx2[w] = bj.z; rjy2[w] = bj.w;
            rja[w]  = sar[j];
            asm volatile("" : "+v"(rjx1[w]), "+v"(rjy1[w]), "+v"(rjx2[w]),
                              "+v"(rjy2[w]), "+v"(rja[w]));   // pin: no LDS remat
        }
        for (int i = wv; i < scanN; i += 16) {
            const float4 bp = sbox4[i];                  // 1 broadcast b128
            const float pa = sar[i];                     // 1 broadcast b32
            const int wlo = i >> 6;                      // diagonal word
#pragma unroll
            for (int w = 0; w < 8; ++w) {
                if (w >= wlo) {                          // wave-uniform skip (upper tri)
                    const int j = w * 64 + ln;
                    const bool jv = (j < scanN) && (j != i);
                    const float ix1 = fmaxf(bp.x, rjx1[w]), iy1 = fmaxf(bp.y, rjy1[w]);
                    const float ix2 = fminf(bp.z, rjx2[w]), iy2 = fminf(bp.w, rjy2[w]);
                    const bool ov = jv && (ix2 > ix1) && (iy2 > iy1);
                    bool sup = false;
                    if (__any(ov)) {
                        const float inter = fmaxf(ix2 - ix1, 0.f) * fmaxf(iy2 - iy1, 0.f);
                        const float iou = inter / (pa + rja[w] - inter + 1e-8f); // ref order
                        sup = ov && (iou > IOU_THR);
                    }
                    const u64 bal = __ballot(sup);       // one live ballot at a time
                    if (ln == 0) mask[i][w] = bal;
                }
            }
        }
    }
    __syncthreads();

    // --- phase 8: chunked greedy resolve (wave 0) ---
    if (wv == 0) {
        u64 remv[8] = {0, 0, 0, 0, 0, 0, 0, 0};
        int cnt = 0;
#pragma unroll
        for (int c = 0; c < 8; ++c) {                   // full unroll: static remv[c]
            if (cnt < MAXDET) {
                const int i = c * 64 + ln;
                const bool valid = (i < scanN);
                u64 alive = __ballot(valid && !((remv[c] >> ln) & 1ULL));
                const u64 sub = valid ? mask[i][c] : 0ULL;   // my column == my row (sym)
                u64 keptM = 0ULL;
                const int cbase = cnt;
                while (alive) {
                    const int f = __ffsll((unsigned long long)alive) - 1;
                    keptM |= (1ULL << f);
                    ++cnt;
                    if (cnt >= MAXDET) break;
                    const bool meSup = ((sub >> f) & 1ULL) != 0ULL;
                    const u64 supM = __ballot(meSup);
                    alive &= ~(supM | (1ULL << f));
                }
                if ((keptM >> ln) & 1ULL) {
                    const int pos = cbase + __popcll(keptM & ((1ULL << ln) - 1ULL));
                    const u64 kk = keyS[i];
                    ksc[pos] = __uint_as_float((u32)(kk >> 32));
                    kix[pos] = (int)(0xFFFFFFFFu - (u32)kk);
                }
                if (cnt < MAXDET && c < 7) {            // propagate removals forward
#pragma unroll
                    for (int w = 0; w < 8; ++w) {
                        if (w > c) {                    // only future-chunk words
                            u64 x = ((keptM >> ln) & 1ULL) ? mask[c * 64 + ln][w] : 0ULL;
#pragma unroll
                            for (int m = 1; m < 64; m <<= 1)
                                x |= (u64)__shfl_xor((long long)x, m);
                            remv[w] |= x;
                        }
                    }
                }
            }
        }
        if (ln == 0) cntSh = cnt;
    }
    __syncthreads();

    // --- phase 9: write out ---
    const int cnt = cntSh;
    for (int k2 = tid; k2 < cnt; k2 += 1024) {
        keptIdx[bc * MAXDET + k2]   = kix[k2];
        keptScore[bc * MAXDET + k2] = ksc[k2];
    }
    if (tid == 0) {
        keptCnt[bc] = cnt;
        flagInc[bc] = (raw > CAP
                       || flagSh
                       || (cnt < MAXDET && totalCand[bc] > use)   // pool cut by T0
                       || (cnt < MAXDET && use > scanN)           // window exhausted
                      ) ? 1 : 0;
    }
}

// ==================== slow path (round-1, verified) ====================

__device__ __forceinline__ void combineMax(float& bs, int& bi, float os, int oi) {
    if (os > bs || (os == bs && oi < bi)) { bs = os; bi = oi; }
}

template<int NPT>
__global__ __launch_bounds__(BS) void nms_slow_kernel(
    const float* __restrict__ boxes, const float* __restrict__ cls,
    const float* __restrict__ cent, int B, int N, int C,
    int* __restrict__ keptIdx, float* __restrict__ keptScore, int* __restrict__ keptCnt,
    const int* __restrict__ flagInc)
{
    const int bc = blockIdx.x;
    if (flagInc != nullptr && flagInc[bc] == 0) return;   // fast path was complete
    const int b   = bc / C;
    const int c   = bc - b * C;
    const int tid = threadIdx.x;

    const float* __restrict__ clsb  = cls  + (size_t)b * N * C + c;
    const float* __restrict__ centb = cent + (size_t)b * N;
    const float* __restrict__ boxb  = boxes + (size_t)b * N * 4;

    float s[NPT];
#pragma unroll
    for (int j = 0; j < NPT; ++j) {
        int n = tid + j * BS;
        float v = -1.0f;
        if (n < N) {
            float cv = clsb[(size_t)n * C];
            if (cv > SCORE_THR) v = sqrtf(cv * centb[n]);
        }
        s[j] = v;
    }

    __shared__ float kx1[MAXDET], ky1[MAXDET], kx2[MAXDET], ky2[MAXDET];
    __shared__ float kscore[MAXDET];
    __shared__ int   kidx[MAXDET];
    __shared__ float redS[BS / 64];
    __shared__ int   redI[BS / 64];
    __shared__ float pbox[4];
    __shared__ float pscoreSh;
    __shared__ int   ctrl;
    __shared__ int   supFlag;

    const int lane = tid & 63;
    const int wid  = tid >> 6;
    const int NW   = BS / 64;
    int cnt = 0;

    const int maxIter = N + MAXDET + 2;
    for (int iter = 0; iter < maxIter; ++iter) {
        float bs = -1.0f; int bi = 0x7fffffff;
#pragma unroll
        for (int j = 0; j < NPT; ++j) {
            if (s[j] > bs) { bs = s[j]; bi = tid + j * BS; }
        }
        for (int m = 1; m < 64; m <<= 1) {
            float os = __shfl_xor(bs, m);
            int   oi = __shfl_xor(bi, m);
            combineMax(bs, bi, os, oi);
        }
        if (lane == 0) { redS[wid] = bs; redI[wid] = bi; }
        __syncthreads();
        if (tid == 0) {
            float gs = redS[0]; int gi = redI[0];
            for (int w = 1; w < NW; ++w) combineMax(gs, gi, redS[w], redI[w]);
            supFlag = 0;
            if (gs <= 0.0f) {
                ctrl = -1;
            } else {
                ctrl = gi; pscoreSh = gs;
                const float4 bx = *reinterpret_cast<const float4*>(boxb + (size_t)gi * 4);
                pbox[0] = bx.x; pbox[1] = bx.y; pbox[2] = bx.z; pbox[3] = bx.w;
            }
        }
        __syncthreads();
        const int P = ctrl;
        if (P < 0) break;

        if ((P & (BS - 1)) == tid) {
            const int jp = P >> 10;
#pragma unroll
            for (int j = 0; j < NPT; ++j) if (j == jp) s[j] = -1.0f;
        }

        if (tid < cnt) {
            const float px1 = pbox[0], py1 = pbox[1], px2 = pbox[2], py2 = pbox[3];
            const float qx1 = kx1[tid], qy1 = ky1[tid], qx2 = kx2[tid], qy2 = ky2[tid];
            const float ix1 = fmaxf(qx1, px1), iy1 = fmaxf(qy1, py1);
            const float ix2 = fminf(qx2, px2), iy2 = fminf(qy2, py2);
            const float inter = fmaxf(ix2 - ix1, 0.0f) * fmaxf(iy2 - iy1, 0.0f);
            const float aq = (qx2 - qx1) * (qy2 - qy1);
            const float ap = (px2 - px1) * (py2 - py1);
            const float iou = inter / (aq + ap - inter + 1e-8f);
            if (iou > IOU_THR) supFlag = 1;
        }
        __syncthreads();
        if (supFlag == 0) {
            if (tid == 0) {
                kx1[cnt] = pbox[0]; ky1[cnt] = pbox[1];
                kx2[cnt] = pbox[2]; ky2[cnt] = pbox[3];
                kscore[cnt] = pscoreSh; kidx[cnt] = P;
            }
            ++cnt;
            if (cnt == MAXDET) break;
        }
    }

    for (int k = tid; k < cnt; k += BS) {
        keptIdx[(size_t)bc * MAXDET + k]   = kidx[k];
        keptScore[(size_t)bc * MAXDET + k] = kscore[k];
    }
    if (tid == 0) keptCnt[bc] = cnt;
}

// ========== final top-300: ADAPTIVE bucket sort of C*300 kept keys ==========
// ROUND-15: kept scores cluster in ~[0.97, 1.0) (top-300 of ~1075), so the
// fixed [0.9,1.0) bucket map used ~25% of buckets (lambda~20) -> serial
// scattered-LDS insertion sort dominated (~45us inferred from the pipeline
// ledger). Fix: reduce min/max score bits over the block's keys, map buckets
// over the ACTUAL range (64-bit mul/div, monotonic) -> lambda~4.7 balanced.
// Any monotonic map is exactly correct: per-bucket insertion sort +
// concatenation reproduces the exact global descending key order.
__global__ __launch_bounds__(1024) void topk_kernel(
    const float* __restrict__ boxes, const int* __restrict__ keptIdx,
    const float* __restrict__ keptScore, const int* __restrict__ keptCnt,
    int B, int N, int C, float* __restrict__ out)
{
    const int b   = blockIdx.x;
    const int tid = threadIdx.x;
    const int wv  = tid >> 6;
    const int ln  = tid & 63;

    __shared__ int cnts[16];
    __shared__ int cntA[NBUCK];
    __shared__ int bbS[NBUCK];
    __shared__ int wsum[16];
    __shared__ u32 wmin[16], wmax[16];
    __shared__ u64 sorted[16 * MAXDET];     // 37.5 KB
    __shared__ int totalSh;

    if (tid < 16) cnts[tid] = (tid < C) ? keptCnt[b * C + tid] : 0;
    cntA[tid] = 0;
    __syncthreads();
    if (tid == 0) {
        int t = 0;
        for (int c = 0; c < C; ++c) t += cnts[c];
        totalSh = t;
    }

    // load keys (5 items/thread max: 16*300/1024 = 4.69) + local min/max bits
    const int TOT = C * MAXDET;
    u64 mk[5]; int mb[5], mr[5];
    u32 lmin = 0xFFFFFFFFu, lmax = 0u;
#pragma unroll
    for (int t = 0; t < 5; ++t) {
        mb[t] = -1;
        const int i = tid + t * 1024;
        if (i < TOT) {
            const int c = i / MAXDET;
            const int k = i - c * MAXDET;
            if (k < cnts[c]) {
                const float sc = keptScore[(b * C + c) * MAXDET + k];
                const u32 fl = (u32)(c * N + keptIdx[(b * C + c) * MAXDET + k]);
                mk[t] = ((u64)__float_as_uint(sc) << 32) | (0xFFFFFFFFu - fl);
                mb[t] = 0;                       // mark valid; bucket set below
                const u32 bits = (u32)(mk[t] >> 32);
                lmin = min(lmin, bits);
                lmax = max(lmax, bits);
            }
        }
    }
    // block-wide min/max reduce (wave shfl + LDS)
#pragma unroll
    for (int m = 1; m < 64; m <<= 1) {
        lmin = min(lmin, (u32)__shfl_xor((int)lmin, m));
        lmax = max(lmax, (u32)__shfl_xor((int)lmax, m));
    }
    if (ln == 0) { wmin[wv] = lmin; wmax[wv] = lmax; }
    __syncthreads();
    u32 gmin = wmin[0], gmax = wmax[0];
#pragma unroll
    for (int w = 1; w < 16; ++w) { gmin = min(gmin, wmin[w]); gmax = max(gmax, wmax[w]); }
    const u64 range1 = (u64)(gmax - gmin) + 1;   // >= 1

    // bucket + rank (adaptive map: higher bits -> lower bucket index)
#pragma unroll
    for (int t = 0; t < 5; ++t) {
        if (mb[t] == 0) {
            const u32 bits = (u32)(mk[t] >> 32);
            const int bk = (NBUCK - 1) - (int)(((u64)(bits - gmin) * NBUCK) / range1);
            mb[t] = bk;
            mr[t] = atomicAdd(&cntA[bk], 1);
        } else {
            mb[t] = -1;
        }
    }
    __syncthreads();

    // exclusive prefix over buckets (wave shfl-scan, 3 barriers)
    const int own = cntA[tid];
    int inc = own;
#pragma unroll
    for (int d = 1; d < 64; d <<= 1) {
        const int t = __shfl_up(inc, d);
        if (ln >= d) inc += t;
    }
    if (ln == 63) wsum[wv] = inc;
    __syncthreads();
    if (wv == 0) {
        int v = (ln < 16) ? wsum[ln] : 0;
#pragma unroll
        for (int d = 1; d < 16; d <<= 1) {
            const int t = __shfl_up(v, d);
            if (ln >= d) v += t;
        }
        if (ln < 16) wsum[ln] = v;
    }
    __syncthreads();
    const int wbase  = (wv == 0) ? 0 : wsum[wv - 1];
    const int myBase = wbase + inc - own;
    bbS[tid] = myBase;
    __syncthreads();

    // scatter
#pragma unroll
    for (int t = 0; t < 5; ++t)
        if (mb[t] >= 0) sorted[bbS[mb[t]] + mr[t]] = mk[t];
    __syncthreads();

    // per-bucket insertion sort (descending)
    {
        const int lo = myBase;
        const int hi = lo + own;
        if (own >= 2) {
            for (int a = lo + 1; a < hi; ++a) {
                const u64 kk = sorted[a];
                int p = a - 1;
                while (p >= lo && sorted[p] < kk) { sorted[p + 1] = sorted[p]; --p; }
                sorted[p + 1] = kk;
            }
        }
    }
    __syncthreads();

    // write top-300 directly
    const int total = totalSh;
    if (tid < MAXDET) {
        float4 bx = make_float4(-1.0f, -1.0f, -1.0f, -1.0f);
        float so = -1.0f, lo2 = -1.0f;
        if (tid < total) {
            const u64 kk = sorted[tid];
            so = __uint_as_float((u32)(kk >> 32));
            const int fl = (int)(0xFFFFFFFFu - (u32)kk);
            const int label  = fl / N;
            const int anchor = fl - label * N;
            bx = *reinterpret_cast<const float4*>(boxes + ((size_t)b * N + anchor) * 4);
            lo2 = (float)label;
        }
        *reinterpret_cast<float4*>(out + (size_t)(b * MAXDET + tid) * 4) = bx;
        out[(size_t)B * MAXDET * 4 + b * MAXDET + tid] = so;
        out[(size_t)B * MAXDET * 5 + b * MAXDET + tid] = lo2;
    }
}

// ============================ launcher ============================

extern "C" void kernel_launch(void* const* d_in, const int* in_sizes, int n_in,
                              void* d_out, int out_size, void* d_ws, size_t ws_size,
                              hipStream_t stream) {
    const float* boxes = (const float*)d_in[0];
    const float* cls   = (const float*)d_in[1];
    const float* cent  = (const float*)d_in[2];
    float* out = (float*)d_out;

    const int B = out_size / (MAXDET * 6);
    if (B <= 0) return;
    const int N = in_sizes[2] / B;
    const int C = in_sizes[1] / in_sizes[2];
    if (N <= 0 || C <= 0 || C > 16) return;
    const int BC = B * C;

    char* base = (char*)d_ws;
    size_t off = 0;
    int*   keptIdx   = (int*)(base + off);   off += (size_t)BC * MAXDET * sizeof(int);
    float* keptScore = (float*)(base + off); off += (size_t)BC * MAXDET * sizeof(float);
    int*   keptCnt   = (int*)(base + off);   off += (size_t)BC * sizeof(int);
    int*   flagInc   = (int*)(base + off);   off += (size_t)BC * sizeof(int);
    const size_t slowNeed = off;
    int*   cntRaw    = (int*)(base + off);   off += (size_t)BC * sizeof(int);
    int*   totalCand = (int*)(base + off);   off += (size_t)BC * sizeof(int);
    off = (off + 7) & ~(size_t)7;
    u64*   candPacked = (u64*)(base + off);  off += (size_t)BC * CAP * sizeof(u64);
    const size_t fastNeed = off;

    const int nptNeeded = (N + BS - 1) / BS;
    if (nptNeeded > 64) return;

    const bool fast = (C == 16) && (ws_size >= fastNeed);

    if (fast) {
        hipMemsetAsync(cntRaw, 0, 2 * (size_t)BC * sizeof(int), stream);
        score_compact_kernel<<<B * SPLIT, 256, 0, stream>>>(
            cls, cent, N, C, candPacked, cntRaw, totalCand);
        sort_nms_kernel<<<BC, 1024, 0, stream>>>(
            boxes, candPacked, cntRaw, totalCand, N, C,
            keptIdx, keptScore, keptCnt, flagInc);
        if (nptNeeded <= 49)
            nms_slow_kernel<49><<<BC, BS, 0, stream>>>(boxes, cls, cent, B, N, C,
                                                       keptIdx, keptScore, keptCnt, flagInc);
        else
            nms_slow_kernel<64><<<BC, BS, 0, stream>>>(boxes, cls, cent, B, N, C,
                                                       keptIdx, keptScore, keptCnt, flagInc);
    } else {
        if (ws_size < slowNeed) return;
        if (nptNeeded <= 49)
            nms_slow_kernel<49><<<BC, BS, 0, stream>>>(boxes, cls, cent, B, N, C,
                                                       keptIdx, keptScore, keptCnt, nullptr);
        else
            nms_slow_kernel<64><<<BC, BS, 0, stream>>>(boxes, cls, cent, B, N, C,
                                                       keptIdx, keptScore, keptCnt, nullptr);
    }

    topk_kernel<<<B, 1024, 0, stream>>>(boxes, keptIdx, keptScore, keptCnt, B, N, C, out);
}